// Round 1
// baseline (5779.263 us; speedup 1.0000x reference)
//
#include <hip/hip_runtime.h>
#include <cmath>
#include <cstddef>

// ---------------------------------------------------------------------------
// Decoder (Transformer-XL style relative attention), fp32 baseline.
// D=1024, H=16, HD=64, L=4, S=T=1024, C=1000.
//
// Relative-position trick: R[2i]=sin((q-k)w_i), R[2i+1]=cos((q-k)w_i) terms are
// folded into an augmented 128-dim QK dot product:
//   Q'[0:64]   = q_row + u_h
//   Q'[64+2i]  = e_{2i} sin(q w_i) + e_{2i+1} cos(q w_i),  e = q_row + v_h
//   Q'[64+2i+1]= e_{2i+1} sin(q w_i) - e_{2i} cos(q w_i)
//   K'[0:64]   = k_row
//   K'[64+2i]  = cos(k w_i);  K'[64+2i+1] = sin(k w_i)
// Then s[h,q,k] = Q'[h,q] . K'[h,k]  (exact trig identity).
// ---------------------------------------------------------------------------

#define DMODEL 1024
#define SEQ    1024

// ------------------------- generic fp32 GEMM -------------------------------
// C[M,N] = A[M,K] @ B[K,N] (+bias) (+ELU). M,N mult of 64, K mult of 16.
__global__ __launch_bounds__(256) void gemm_f32(
    const float* __restrict__ A, const float* __restrict__ B,
    const float* __restrict__ bias, float* __restrict__ C,
    int M, int N, int K, int act)
{
    __shared__ float As[16][68];   // [k][m], padded
    __shared__ float Bs[16][68];   // [k][n], padded

    const int t  = threadIdx.x;
    const int tx = t & 15;
    const int ty = t >> 4;
    const int row0 = blockIdx.y * 64;
    const int col0 = blockIdx.x * 64;

    // A-load mapping: m = t>>2 (0..63), k4 = (t&3)*4
    const int am = t >> 2;
    const int ak = (t & 3) << 2;
    // B-load mapping: k = t>>4 (0..15), n4 = (t&15)*4
    const int bk = t >> 4;
    const int bn = (t & 15) << 2;

    const float* Aptr = A + (size_t)(row0 + am) * K + ak;
    const float* Bptr = B + (size_t)bk * N + col0 + bn;

    float acc[4][4];
#pragma unroll
    for (int i = 0; i < 4; ++i)
#pragma unroll
        for (int j = 0; j < 4; ++j) acc[i][j] = 0.f;

    for (int k0 = 0; k0 < K; k0 += 16) {
        const float4 av = *(const float4*)(Aptr + k0);
        const float4 bv = *(const float4*)(Bptr + (size_t)k0 * N);
        __syncthreads();
        As[ak + 0][am] = av.x;
        As[ak + 1][am] = av.y;
        As[ak + 2][am] = av.z;
        As[ak + 3][am] = av.w;
        *(float4*)&Bs[bk][bn] = bv;
        __syncthreads();
#pragma unroll
        for (int k = 0; k < 16; ++k) {
            const float4 a = *(const float4*)&As[k][ty << 2];
            const float4 b = *(const float4*)&Bs[k][tx << 2];
            const float ar[4] = {a.x, a.y, a.z, a.w};
            const float br[4] = {b.x, b.y, b.z, b.w};
#pragma unroll
            for (int i = 0; i < 4; ++i)
#pragma unroll
                for (int j = 0; j < 4; ++j)
                    acc[i][j] = fmaf(ar[i], br[j], acc[i][j]);
        }
    }

#pragma unroll
    for (int i = 0; i < 4; ++i) {
        const int rr = row0 + (ty << 2) + i;
        float4 v;
        float* vp = &v.x;
#pragma unroll
        for (int j = 0; j < 4; ++j) {
            const int cc = col0 + (tx << 2) + j;
            float val = acc[i][j];
            if (bias) val += bias[cc];
            if (act == 1) val = val > 0.f ? val : expm1f(val);   // ELU
            vp[j] = val;
        }
        *(float4*)&C[(size_t)rr * N + col0 + (tx << 2)] = v;
    }
}

// --------------------- build augmented Q'/K' -------------------------------
// qp,kp: (S, D) projections.  u,v: (H,HD).  Qa,Ka: (H, S, 128)
__global__ __launch_bounds__(256) void build_aug(
    const float* __restrict__ qp, const float* __restrict__ kp,
    const float* __restrict__ u, const float* __restrict__ v,
    float* __restrict__ Qa, float* __restrict__ Ka)
{
    const int s = blockIdx.x;
    const int h = blockIdx.y * 4 + threadIdx.y;
    const int t = threadIdx.x;   // 0..63

    const float* qrow = qp + (size_t)s * DMODEL + h * 64;
    const float* krow = kp + (size_t)s * DMODEL + h * 64;
    float* Qrow = Qa + ((size_t)h * SEQ + s) * 128;
    float* Krow = Ka + ((size_t)h * SEQ + s) * 128;

    Qrow[t] = qrow[t] + u[h * 64 + t];
    Krow[t] = krow[t];

    if (t < 32) {
        // w_i = 10000^(-2i/64) = exp(-i * ln(10000)/32)
        const float w   = expf((float)t * (-9.210340371976184f / 32.f));
        const float ang = (float)s * w;
        const float sn = sinf(ang);
        const float cs = cosf(ang);
        const float e0 = qrow[2 * t]     + v[h * 64 + 2 * t];
        const float e1 = qrow[2 * t + 1] + v[h * 64 + 2 * t + 1];
        Qrow[64 + 2 * t]     = e0 * sn + e1 * cs;
        Qrow[64 + 2 * t + 1] = e1 * sn - e0 * cs;
        Krow[64 + 2 * t]     = cs;
        Krow[64 + 2 * t + 1] = sn;
    }
}

// --------------------------- flash attention -------------------------------
// Qa,Ka: (H,S,128). V: (S,D) (head h uses cols h*64..h*64+63). O: (S,D).
#define FQB 32
#define FKB 32
__global__ __launch_bounds__(256) void flash_attn(
    const float* __restrict__ Qa, const float* __restrict__ Ka,
    const float* __restrict__ V, float* __restrict__ O, int causal)
{
    const int h   = blockIdx.y;
    const int qb0 = blockIdx.x * FQB;
    const int t   = threadIdx.x;

    __shared__ float Qs[FQB][132];
    __shared__ float Ks[FKB][132];
    __shared__ float Vs[FKB][64];
    __shared__ float Ps[FQB][33];

    const float* Qbase = Qa + ((size_t)h * SEQ + qb0) * 128;
    for (int i = t; i < FQB * 32; i += 256) {
        const int rr = i >> 5, c4 = (i & 31) << 2;
        *(float4*)&Qs[rr][c4] = *(const float4*)(Qbase + rr * 128 + c4);
    }

    const int r  = t >> 3;        // query row 0..31
    const int kg = t & 7;         // key group (4 keys each)
    const int c0 = kg * 8;        // o-columns owned

    float m = -INFINITY, lsum = 0.f;
    float o[8];
#pragma unroll
    for (int j = 0; j < 8; ++j) o[j] = 0.f;

    const int kend = causal ? (qb0 + FQB) : SEQ;
    for (int kb0 = 0; kb0 < kend; kb0 += FKB) {
        __syncthreads();
        const float* Kbase = Ka + ((size_t)h * SEQ + kb0) * 128;
        for (int i = t; i < FKB * 32; i += 256) {
            const int rr = i >> 5, c4 = (i & 31) << 2;
            *(float4*)&Ks[rr][c4] = *(const float4*)(Kbase + rr * 128 + c4);
        }
        for (int i = t; i < FKB * 16; i += 256) {
            const int rr = i >> 4, c4 = (i & 15) << 2;
            *(float4*)&Vs[rr][c4] =
                *(const float4*)(V + (size_t)(kb0 + rr) * DMODEL + h * 64 + c4);
        }
        __syncthreads();

        float sacc[4] = {0.f, 0.f, 0.f, 0.f};
#pragma unroll 8
        for (int d = 0; d < 128; d += 4) {
            const float4 qv = *(const float4*)&Qs[r][d];
#pragma unroll
            for (int kk = 0; kk < 4; ++kk) {
                const float4 kv = *(const float4*)&Ks[kg * 4 + kk][d];
                sacc[kk] += qv.x * kv.x + qv.y * kv.y + qv.z * kv.z + qv.w * kv.w;
            }
        }
        if (causal) {
#pragma unroll
            for (int kk = 0; kk < 4; ++kk)
                if (kb0 + kg * 4 + kk > qb0 + r) sacc[kk] = -INFINITY;
        }

        float bmax = fmaxf(fmaxf(sacc[0], sacc[1]), fmaxf(sacc[2], sacc[3]));
        bmax = fmaxf(bmax, __shfl_xor(bmax, 1));
        bmax = fmaxf(bmax, __shfl_xor(bmax, 2));
        bmax = fmaxf(bmax, __shfl_xor(bmax, 4));
        const float mnew = fmaxf(m, bmax);
        const float f = __expf(m - mnew);

        float psum = 0.f;
#pragma unroll
        for (int kk = 0; kk < 4; ++kk) {
            const float p = __expf(sacc[kk] - mnew);
            Ps[r][kg * 4 + kk] = p;
            psum += p;
        }
        psum += __shfl_xor(psum, 1);
        psum += __shfl_xor(psum, 2);
        psum += __shfl_xor(psum, 4);
        lsum = lsum * f + psum;
        m = mnew;
        __syncthreads();

#pragma unroll
        for (int j = 0; j < 8; ++j) o[j] *= f;
#pragma unroll 4
        for (int kk = 0; kk < FKB; ++kk) {
            const float p  = Ps[r][kk];
            const float4 v0 = *(const float4*)&Vs[kk][c0];
            const float4 v1 = *(const float4*)&Vs[kk][c0 + 4];
            o[0] += p * v0.x; o[1] += p * v0.y; o[2] += p * v0.z; o[3] += p * v0.w;
            o[4] += p * v1.x; o[5] += p * v1.y; o[6] += p * v1.z; o[7] += p * v1.w;
        }
    }

    const float inv = 1.f / lsum;
    float* Orow = O + (size_t)(qb0 + r) * DMODEL + h * 64 + c0;
    float4 w0, w1;
    w0.x = o[0] * inv; w0.y = o[1] * inv; w0.z = o[2] * inv; w0.w = o[3] * inv;
    w1.x = o[4] * inv; w1.y = o[5] * inv; w1.z = o[6] * inv; w1.w = o[7] * inv;
    *(float4*)Orow       = w0;
    *(float4*)(Orow + 4) = w1;
}

// ---------------------- residual + LayerNorm -------------------------------
// out[s,:] = LN(a[s,:] + b[s,:]) * g + be
__global__ __launch_bounds__(256) void ln_residual(
    const float* __restrict__ a, const float* __restrict__ b,
    const float* __restrict__ g, const float* __restrict__ be,
    float* __restrict__ out)
{
    const int srow = blockIdx.x;
    const int t = threadIdx.x;
    const float* pa = a + (size_t)srow * DMODEL;
    const float* pb = b + (size_t)srow * DMODEL;

    float x[4];
    float s = 0.f, s2 = 0.f;
#pragma unroll
    for (int j = 0; j < 4; ++j) {
        const int idx = t + 256 * j;
        x[j] = pa[idx] + pb[idx];
        s  += x[j];
        s2 += x[j] * x[j];
    }
#pragma unroll
    for (int off = 1; off < 64; off <<= 1) {
        s  += __shfl_xor(s, off);
        s2 += __shfl_xor(s2, off);
    }
    __shared__ float rs[4], rs2[4];
    const int wv = t >> 6;
    if ((t & 63) == 0) { rs[wv] = s; rs2[wv] = s2; }
    __syncthreads();
    s  = rs[0] + rs[1] + rs[2] + rs[3];
    s2 = rs2[0] + rs2[1] + rs2[2] + rs2[3];

    const float mean = s * (1.f / DMODEL);
    const float var  = s2 * (1.f / DMODEL) - mean * mean;
    const float rstd = rsqrtf(var + 1e-5f);

    float* po = out + (size_t)srow * DMODEL;
#pragma unroll
    for (int j = 0; j < 4; ++j) {
        const int idx = t + 256 * j;
        po[idx] = (x[j] - mean) * rstd * g[idx] + be[idx];
    }
}

// --------------------------- output head -----------------------------------
__global__ __launch_bounds__(1024) void head_softmax(
    const float* __restrict__ buf, const float* __restrict__ Wout,
    const float* __restrict__ bout, float* __restrict__ out)
{
    const int t = threadIdx.x;
    __shared__ float xs[DMODEL];
    xs[t] = buf[(size_t)(SEQ - 1) * DMODEL + t];
    __syncthreads();

    float acc = -INFINITY;
    if (t < 1000) {
        float a = 0.f;
        for (int d = 0; d < DMODEL; ++d)
            a = fmaf(xs[d], Wout[(size_t)d * 1000 + t], a);
        acc = a + bout[t];
    }

    float mx = acc;
#pragma unroll
    for (int off = 1; off < 64; off <<= 1) mx = fmaxf(mx, __shfl_xor(mx, off));
    __shared__ float red[16];
    const int wv = t >> 6;
    if ((t & 63) == 0) red[wv] = mx;
    __syncthreads();
    mx = red[0];
#pragma unroll
    for (int w = 1; w < 16; ++w) mx = fmaxf(mx, red[w]);

    const float p = (t < 1000) ? expf(acc - mx) : 0.f;
    float ssum = p;
#pragma unroll
    for (int off = 1; off < 64; off <<= 1) ssum += __shfl_xor(ssum, off);
    __syncthreads();
    __shared__ float red2[16];
    if ((t & 63) == 0) red2[wv] = ssum;
    __syncthreads();
    float tot = 0.f;
#pragma unroll
    for (int w = 0; w < 16; ++w) tot += red2[w];

    if (t < 1000) out[t] = p / tot;
}

// ---------------------------------------------------------------------------
extern "C" void kernel_launch(void* const* d_in, const int* in_sizes, int n_in,
                              void* d_out, int out_size, void* d_ws, size_t ws_size,
                              hipStream_t stream)
{
    const float* seq   = (const float*)d_in[0];
    const float* encv  = (const float*)d_in[1];
    const float* enck  = (const float*)d_in[2];
    const float* Wq_s  = (const float*)d_in[3];
    const float* Wk_s  = (const float*)d_in[4];
    const float* Wv_s  = (const float*)d_in[5];
    const float* Wo_s  = (const float*)d_in[6];
    const float* bo_s  = (const float*)d_in[7];
    const float* u_s   = (const float*)d_in[8];
    const float* v_s   = (const float*)d_in[9];
    const float* gn    = (const float*)d_in[10];
    const float* bn    = (const float*)d_in[11];
    const float* Wq_c  = (const float*)d_in[12];
    const float* Wk_c  = (const float*)d_in[13];
    const float* Wv_c  = (const float*)d_in[14];
    const float* Wo_c  = (const float*)d_in[15];
    const float* bo_c  = (const float*)d_in[16];
    const float* u_c   = (const float*)d_in[17];
    const float* v_c   = (const float*)d_in[18];
    const float* g0    = (const float*)d_in[19];
    const float* b0    = (const float*)d_in[20];
    const float* g1    = (const float*)d_in[21];
    const float* b1    = (const float*)d_in[22];
    const float* W1    = (const float*)d_in[23];
    const float* bf1   = (const float*)d_in[24];
    const float* W2    = (const float*)d_in[25];
    const float* bf2   = (const float*)d_in[26];
    const float* Wout  = (const float*)d_in[27];
    const float* bout  = (const float*)d_in[28];
    (void)in_sizes; (void)n_in; (void)out_size; (void)ws_size;

    float* ws = (float*)d_ws;
    const size_t M1 = (size_t)1024 * 1024;
    float* buf = ws;             // current activations (S,D)
    float* A1  = ws + 1 * M1;    // q proj / attn-proj out (AP)
    float* A2  = ws + 2 * M1;    // k proj / X2
    float* A3  = ws + 3 * M1;    // v proj
    float* QA  = ws + 4 * M1;    // (H,S,128)  [FFN hidden reuses QA+KA = 4M floats]
    float* KA  = ws + 6 * M1;    // (H,S,128)
    float* AO  = ws + 8 * M1;    // attention output (S,D)
    float* X1  = ws + 9 * M1;    // post-self-attn LN
    float* AP  = A1;
    float* X2  = A2;
    float* FH  = QA;             // FFN hidden (S, 4D) = 4M floats

    hipMemcpyAsync(buf, seq, M1 * sizeof(float), hipMemcpyDeviceToDevice, stream);

    const dim3 gsq(16, 16);          // 1024x1024 GEMM
    const dim3 gff1(64, 16);         // N=4096
    const dim3 augGrid(SEQ, 4);
    const dim3 augBlk(64, 4);
    const dim3 flashGrid(SEQ / FQB, 16);

    for (int l = 0; l < 4; ++l) {
        const size_t wOff = (size_t)l * M1;
        const size_t vOff = (size_t)l * 1024;

        // ---- self attention (causal) ----
        gemm_f32<<<gsq, 256, 0, stream>>>(buf, Wq_s + wOff, nullptr, A1, 1024, 1024, 1024, 0);
        gemm_f32<<<gsq, 256, 0, stream>>>(buf, Wk_s + wOff, nullptr, A2, 1024, 1024, 1024, 0);
        gemm_f32<<<gsq, 256, 0, stream>>>(buf, Wv_s + wOff, nullptr, A3, 1024, 1024, 1024, 0);
        build_aug<<<augGrid, augBlk, 0, stream>>>(A1, A2, u_s + vOff, v_s + vOff, QA, KA);
        flash_attn<<<flashGrid, 256, 0, stream>>>(QA, KA, A3, AO, 1);
        gemm_f32<<<gsq, 256, 0, stream>>>(AO, Wo_s + wOff, bo_s + vOff, AP, 1024, 1024, 1024, 0);
        ln_residual<<<SEQ, 256, 0, stream>>>(AP, buf, gn + vOff, bn + vOff, X1);

        // ---- cross attention ----
        gemm_f32<<<gsq, 256, 0, stream>>>(X1, Wq_c + wOff, nullptr, A1, 1024, 1024, 1024, 0);
        gemm_f32<<<gsq, 256, 0, stream>>>(enck, Wk_c + wOff, nullptr, A2, 1024, 1024, 1024, 0);
        gemm_f32<<<gsq, 256, 0, stream>>>(encv, Wv_c + wOff, nullptr, A3, 1024, 1024, 1024, 0);
        build_aug<<<augGrid, augBlk, 0, stream>>>(A1, A2, u_c + vOff, v_c + vOff, QA, KA);
        flash_attn<<<flashGrid, 256, 0, stream>>>(QA, KA, A3, AO, 0);
        gemm_f32<<<gsq, 256, 0, stream>>>(AO, Wo_c + wOff, bo_c + vOff, AP, 1024, 1024, 1024, 0);
        ln_residual<<<SEQ, 256, 0, stream>>>(AP, X1, g0 + vOff, b0 + vOff, X2);

        // ---- feed forward ----
        gemm_f32<<<gff1, 256, 0, stream>>>(X2, W1 + wOff * 4, bf1 + (size_t)l * 4096, FH,
                                           1024, 4096, 1024, 1);
        gemm_f32<<<gsq, 256, 0, stream>>>(FH, W2 + wOff * 4, bf2 + vOff, AP,
                                          1024, 1024, 4096, 0);
        ln_residual<<<SEQ, 256, 0, stream>>>(AP, X2, g1 + vOff, b1 + vOff, buf);
    }

    head_softmax<<<1, 1024, 0, stream>>>(buf, Wout, bout, (float*)d_out);
}